// Round 12
// baseline (167.998 us; speedup 1.0000x reference)
//
#include <hip/hip_runtime.h>
#include <hip/hip_bf16.h>
#include <math.h>

typedef short bf16x8 __attribute__((ext_vector_type(8)));
typedef float f32x4  __attribute__((ext_vector_type(4)));
#define MFMA16(a,b,c) __builtin_amdgcn_mfma_f32_16x16x32_bf16(a,b,c,0,0,0)

#define EPSF 1e-5f
#define QSC 0.18033688f   // 0.125 * log2(e), folded into Q

#if __has_builtin(__builtin_amdgcn_exp2f)
#define EXP2(x) __builtin_amdgcn_exp2f(x)
#else
#define EXP2(x) exp2f(x)
#endif

__device__ __forceinline__ unsigned int pk2n(float a, float b){
  __hip_bfloat162 h = __float22bfloat162_rn(make_float2(a, b));
  return *reinterpret_cast<unsigned int*>(&h);
}
__device__ __forceinline__ unsigned short bfn(float f){
  __hip_bfloat16 h = __float2bfloat16(f);
  return *reinterpret_cast<unsigned short*>(&h);
}
__device__ __forceinline__ float4 ld4(const float* p){ return *reinterpret_cast<const float4*>(p); }
__device__ __forceinline__ void st4(float* p, float4 v){ *reinterpret_cast<float4*>(p) = v; }

// async global->LDS, 16B per lane; LDS dest = wave-uniform base + lane*16
__device__ __forceinline__ void gl_lds16(const unsigned short* g, unsigned short* l){
  __builtin_amdgcn_global_load_lds(
      (const __attribute__((address_space(1))) unsigned int*)g,
      (__attribute__((address_space(3))) unsigned int*)l, 16, 0, 0);
}

// ---------------- weight f32 -> bf16 ----------------
__global__ __launch_bounds__(256) void wcvt_k(const float* __restrict__ src,
                                              unsigned int* __restrict__ dst){
  int i = blockIdx.x * 256 + threadIdx.x;            // one float4 -> uint2
  float4 v = reinterpret_cast<const float4*>(src)[i];
  uint2 r; r.x = pk2n(v.x, v.y); r.y = pk2n(v.z, v.w);
  reinterpret_cast<uint2*>(dst)[i] = r;
}

// ---------------- fused GroupNorm stats + apply + transpose ----------------
__global__ __launch_bounds__(512) void gn_fused_k(const float* __restrict__ x,
                                                  const float* __restrict__ gnw,
                                                  const float* __restrict__ gnb,
                                                  unsigned short* __restrict__ xnT){
  __shared__ float Xl[2][64*65];
  __shared__ float red[16];
  int blk = blockIdx.x;                       // b*8+g
  int b = blk >> 3, g = blk & 7;
  int tid = threadIdx.x;
  const float4* p4 = reinterpret_cast<const float4*>(x + (size_t)blk * 65536);
  float s1 = 0.f, s2 = 0.f;
  for(int i = tid; i < 16384; i += 512){
    float4 v = p4[i];
    s1 += (v.x + v.y) + (v.z + v.w);
    s2 += v.x*v.x + v.y*v.y + v.z*v.z + v.w*v.w;
  }
  #pragma unroll
  for(int off = 32; off; off >>= 1){ s1 += __shfl_xor(s1, off); s2 += __shfl_xor(s2, off); }
  if((tid & 63) == 0){ red[tid >> 6] = s1; red[8 + (tid >> 6)] = s2; }
  __syncthreads();
  float a = 0.f, b2 = 0.f;
  #pragma unroll
  for(int w = 0; w < 8; w++){ a += red[w]; b2 += red[8 + w]; }
  float mean = a * (1.f / 65536.f);
  float rstd = rsqrtf(b2 * (1.f / 65536.f) - mean * mean + EPSF);
  int half = tid >> 8, t256 = tid & 255;
  int nq = t256 & 15, rr = t256 >> 4;
  int c0 = g * 64;
  for(int it = 0; it < 8; it++){
    int n0 = (it*2 + half) * 64;
    __syncthreads();
    #pragma unroll
    for(int p = 0; p < 4; p++){
      int cl = p * 16 + rr, c = c0 + cl;
      float s = rstd * gnw[c], t = gnb[c] - mean * s;
      float4 v = ld4(x + ((size_t)(b*512 + c))*1024 + n0 + 4*nq);
      Xl[half][(4*nq+0)*65 + cl] = v.x*s + t;
      Xl[half][(4*nq+1)*65 + cl] = v.y*s + t;
      Xl[half][(4*nq+2)*65 + cl] = v.z*s + t;
      Xl[half][(4*nq+3)*65 + cl] = v.w*s + t;
    }
    __syncthreads();
    int n = t256 >> 2, cq = t256 & 3;
    float f[16];
    #pragma unroll
    for(int k = 0; k < 16; k++) f[k] = Xl[half][n*65 + 16*cq + k];
    uint4 w0, w1;
    w0.x = pk2n(f[0],f[1]);  w0.y = pk2n(f[2],f[3]);  w0.z = pk2n(f[4],f[5]);  w0.w = pk2n(f[6],f[7]);
    w1.x = pk2n(f[8],f[9]);  w1.y = pk2n(f[10],f[11]);w1.z = pk2n(f[12],f[13]);w1.w = pk2n(f[14],f[15]);
    unsigned short* dp = xnT + ((size_t)(b*1024 + n0 + n))*512 + c0 + 16*cq;
    *reinterpret_cast<uint4*>(dp)     = w0;
    *reinterpret_cast<uint4*>(dp + 8) = w1;
  }
}

// ---- GEMM core: BK=64, gl_lds staging, XOR-swizzled linear LDS (r10 measured-best) ----

// ---------------- QKV GEMM: Q,K transposed (Q pre-scaled) + V natural ----------------
__global__ __launch_bounds__(256) void qkv_mm(const unsigned short* __restrict__ A,
                                              const unsigned short* __restrict__ Bx,
                                              const float* __restrict__ bias,
                                              unsigned short* __restrict__ T,
                                              unsigned short* __restrict__ V){
  __shared__ __align__(16) unsigned short As[128*64], Bs[128*64];
  int tid = threadIdx.x;
  int n0 = blockIdx.x*128, o0 = blockIdx.y*128, b = blockIdx.z;
  int wid = tid >> 6, wr = wid >> 1, wc = wid & 1, ln = tid & 15, g = (tid >> 4) & 3;
  int l = tid & 63;
  int rsw = (ln & 7) << 3;
  int srow = 32*wid + (l >> 3);
  int scol = (((l & 7) ^ (l >> 3)) << 3);
  const unsigned short* Ag = A  + (size_t)(o0 + srow)*512 + scol;
  const unsigned short* Bg = Bx + ((size_t)(b*1024 + n0 + srow))*512 + scol;
  unsigned short* Asw = As + (32*wid)*64;
  unsigned short* Bsw = Bs + (32*wid)*64;
  f32x4 acc[4][4] = {};
  for(int k0 = 0; k0 < 512; k0 += 64){
    __syncthreads();
    #pragma unroll
    for(int c = 0; c < 4; c++){
      gl_lds16(Ag + (size_t)(8*c)*512 + k0, Asw + (8*c)*64);
      gl_lds16(Bg + (size_t)(8*c)*512 + k0, Bsw + (8*c)*64);
    }
    __syncthreads();
    #pragma unroll
    for(int kh = 0; kh < 2; kh++){
      int ro = (kh*32 + 8*g) ^ rsw;
      bf16x8 af[4], bfv[4];
      #pragma unroll
      for(int mf = 0; mf < 4; mf++)
        af[mf] = *reinterpret_cast<const bf16x8*>(&As[(wr*64 + 16*mf + ln)*64 + ro]);
      #pragma unroll
      for(int nf = 0; nf < 4; nf++)
        bfv[nf] = *reinterpret_cast<const bf16x8*>(&Bs[(wc*64 + 16*nf + ln)*64 + ro]);
      #pragma unroll
      for(int mf = 0; mf < 4; mf++)
        #pragma unroll
        for(int nf = 0; nf < 4; nf++)
          acc[mf][nf] = MFMA16(af[mf], bfv[nf], acc[mf][nf]);
    }
  }
  int obase = o0 + wr*64, nbase = n0 + wc*64;
  __syncthreads();                                    // As/Bs reuse as scratch
  unsigned short* scr = (wid < 2 ? As : Bs) + (wid & 1) * 2560;   // 64 rows x 40 pitch
  float sc = (obase < 512) ? QSC : 1.0f;
  if(obase < 1024){
    #pragma unroll
    for(int h2 = 0; h2 < 2; h2++){
      asm volatile("s_waitcnt lgkmcnt(0)" ::: "memory");
      __builtin_amdgcn_sched_barrier(0);
      #pragma unroll
      for(int mf2 = 0; mf2 < 2; mf2++){
        int mf = 2*h2 + mf2;
        int og = obase + 16*mf + 4*g;
        float b0 = bias[og], b1 = bias[og+1], b2 = bias[og+2], b3 = bias[og+3];
        #pragma unroll
        for(int nf = 0; nf < 4; nf++){
          uint2 pr;
          pr.x = pk2n((acc[mf][nf][0]+b0)*sc, (acc[mf][nf][1]+b1)*sc);
          pr.y = pk2n((acc[mf][nf][2]+b2)*sc, (acc[mf][nf][3]+b3)*sc);
          *reinterpret_cast<uint2*>(&scr[(16*nf + ln)*40 + 16*mf2 + 4*g]) = pr;
        }
      }
      asm volatile("s_waitcnt lgkmcnt(0)" ::: "memory");
      __builtin_amdgcn_sched_barrier(0);
      const unsigned short* rp = &scr[l*40];
      uint4 r0 = *reinterpret_cast<const uint4*>(rp);
      uint4 r1 = *reinterpret_cast<const uint4*>(rp+8);
      uint4 r2 = *reinterpret_cast<const uint4*>(rp+16);
      uint4 r3 = *reinterpret_cast<const uint4*>(rp+24);
      unsigned short* dp = T + ((size_t)(b*1024 + nbase + l))*1024 + obase + 32*h2;
      *reinterpret_cast<uint4*>(dp)    = r0;
      *reinterpret_cast<uint4*>(dp+8)  = r1;
      *reinterpret_cast<uint4*>(dp+16) = r2;
      *reinterpret_cast<uint4*>(dp+24) = r3;
    }
  } else {
    #pragma unroll
    for(int h2 = 0; h2 < 2; h2++){
      asm volatile("s_waitcnt lgkmcnt(0)" ::: "memory");
      __builtin_amdgcn_sched_barrier(0);
      #pragma unroll
      for(int nf2 = 0; nf2 < 2; nf2++){
        int nf = 2*h2 + nf2;
        #pragma unroll
        for(int mf = 0; mf < 4; mf++){
          int og = obase + 16*mf + 4*g;
          #pragma unroll
          for(int r = 0; r < 4; r++)
            scr[(16*mf + 4*g + r)*40 + 16*nf2 + ln] = bfn(acc[mf][nf][r] + bias[og+r]);
        }
      }
      asm volatile("s_waitcnt lgkmcnt(0)" ::: "memory");
      __builtin_amdgcn_sched_barrier(0);
      const unsigned short* rp = &scr[l*40];
      uint4 r0 = *reinterpret_cast<const uint4*>(rp);
      uint4 r1 = *reinterpret_cast<const uint4*>(rp+8);
      uint4 r2 = *reinterpret_cast<const uint4*>(rp+16);
      uint4 r3 = *reinterpret_cast<const uint4*>(rp+24);
      unsigned short* dp = V + ((size_t)(b*512 + obase - 1024 + l))*1024 + nbase + 32*h2;
      *reinterpret_cast<uint4*>(dp)    = r0;
      *reinterpret_cast<uint4*>(dp+8)  = r1;
      *reinterpret_cast<uint4*>(dp+16) = r2;
      *reinterpret_cast<uint4*>(dp+24) = r3;
    }
  }
}

// ---------------- Flash attention: 128 Q-rows/block (2 sub-tiles share staged K/V),
// gload_lds staging, XOR-swizzled LDS, dbuf, 1 barrier/tile, no-max exp2 softmax ----
__global__ __launch_bounds__(256, 4) void attn_bf_k(const unsigned short* __restrict__ T,
                                                    const unsigned short* __restrict__ V,
                                                    unsigned short* __restrict__ attT){
  __shared__ __align__(16) unsigned short KT[2][64*64];
  __shared__ __align__(16) unsigned short Vt[2][64*64];
  __shared__ __align__(16) unsigned int   Pl[4*16*32];
  int tid = threadIdx.x;
  // id = h + 8*n0blk + 64*b : all 8 blocks of a head share id%8 (same XCD)
  int id = blockIdx.x;
  int h = id & 7, n0 = ((id >> 3) & 7) * 128, b = id >> 6;
  int wq = tid >> 6, ln = tid & 15, g = (tid >> 4) & 3;
  int l = tid & 63;
  int nl0 = n0 + wq*16 + ln, nl1 = nl0 + 64;
  const unsigned short* Tb = T + ((size_t)b << 20);
  bf16x8 qa0 = *reinterpret_cast<const bf16x8*>(Tb + (size_t)nl0*1024 + h*64 + 8*g);
  bf16x8 qa1 = *reinterpret_cast<const bf16x8*>(Tb + (size_t)nl0*1024 + h*64 + 32 + 8*g);
  bf16x8 qb0 = *reinterpret_cast<const bf16x8*>(Tb + (size_t)nl1*1024 + h*64 + 8*g);
  bf16x8 qb1 = *reinterpret_cast<const bf16x8*>(Tb + (size_t)nl1*1024 + h*64 + 32 + 8*g);
  f32x4 acc[2][4] = {};
  float l_part[2] = {0.f, 0.f};
  const unsigned short* kg = Tb + 512 + h*64;
  const unsigned short* vg = V + ((size_t)(b*512 + h*64))*1024;
  int pbase = wq*512 + ln*32;
  int psw = (ln & 7) << 2;
  int swz  = (((l & 7) << 3) ^ ((l >> 3) << 3));
  const unsigned short* ksrc = kg + (size_t)(wq*16 + (l>>3))*1024 + swz;
  const unsigned short* vsrc = vg + (size_t)(wq*16 + (l>>3))*1024 + swz;
  int rsw = (ln & 7) << 3;
  int ro0 = (8*g) ^ rsw, ro1 = (32 + 8*g) ^ rsw;
  {
    unsigned short* kb = &KT[0][wq*16*64];
    unsigned short* vb = &Vt[0][wq*16*64];
    gl_lds16(ksrc,            kb);
    gl_lds16(ksrc + 8*1024,   kb + 8*64);
    gl_lds16(vsrc,            vb);
    gl_lds16(vsrc + 8*1024,   vb + 8*64);
  }
  __syncthreads();
  for(int t = 0; t < 16; t++){
    int buf = t & 1;
    if(t < 15){
      int m1 = (t + 1) * 64;
      unsigned short* kb = &KT[buf^1][wq*16*64];
      unsigned short* vb = &Vt[buf^1][wq*16*64];
      gl_lds16(ksrc + (size_t)m1*1024,          kb);
      gl_lds16(ksrc + (size_t)(m1+8)*1024,      kb + 8*64);
      gl_lds16(vsrc + m1,                       vb);
      gl_lds16(vsrc + 8*1024 + m1,              vb + 8*64);
    }
    #pragma unroll
    for(int sub = 0; sub < 2; sub++){
      bf16x8 q0 = sub ? qb0 : qa0;
      bf16x8 q1 = sub ? qb1 : qa1;
      f32x4 sf[4];
      #pragma unroll
      for(int mf = 0; mf < 4; mf++){
        bf16x8 a0 = *reinterpret_cast<const bf16x8*>(&KT[buf][(16*mf + ln)*64 + ro0]);
        bf16x8 a1 = *reinterpret_cast<const bf16x8*>(&KT[buf][(16*mf + ln)*64 + ro1]);
        f32x4 z = {0.f, 0.f, 0.f, 0.f};
        z = MFMA16(a0, q0, z);
        sf[mf] = MFMA16(a1, q1, z);
      }
      float p[16];
      float lp = 0.f;
      #pragma unroll
      for(int mf = 0; mf < 4; mf++)
        #pragma unroll
        for(int r = 0; r < 4; r++){
          float v = EXP2(sf[mf][r]);
          p[mf*4 + r] = v;
          lp += v;
        }
      l_part[sub] += lp;
      #pragma unroll
      for(int mt = 0; mt < 4; mt++){
        Pl[pbase + ((8*mt + 2*g + 0) ^ psw)] = pk2n(p[4*mt + 0], p[4*mt + 1]);
        Pl[pbase + ((8*mt + 2*g + 1) ^ psw)] = pk2n(p[4*mt + 2], p[4*mt + 3]);
      }
      asm volatile("s_waitcnt lgkmcnt(0)" ::: "memory");
      __builtin_amdgcn_sched_barrier(0);
      union { uint4 u; bf16x8 hv; } pb0, pb1;
      pb0.u = *reinterpret_cast<const uint4*>(&Pl[pbase + ((4*g) ^ psw)]);
      pb1.u = *reinterpret_cast<const uint4*>(&Pl[pbase + ((16 + 4*g) ^ psw)]);
      #pragma unroll
      for(int cf = 0; cf < 4; cf++){
        bf16x8 v0 = *reinterpret_cast<const bf16x8*>(&Vt[buf][(16*cf + ln)*64 + ro0]);
        bf16x8 v1 = *reinterpret_cast<const bf16x8*>(&Vt[buf][(16*cf + ln)*64 + ro1]);
        acc[sub][cf] = MFMA16(v0, pb0.hv, acc[sub][cf]);
        acc[sub][cf] = MFMA16(v1, pb1.hv, acc[sub][cf]);
      }
      // sched_barrier keeps sub1's Pl writes from hoisting above sub0's reads
      __builtin_amdgcn_sched_barrier(0);
    }
    __syncthreads();   // drains staging (issued a full tile ago) + fences buf reuse
  }
  #pragma unroll
  for(int sub = 0; sub < 2; sub++){
    float lsum = l_part[sub];
    lsum += __shfl_xor(lsum, 16);
    lsum += __shfl_xor(lsum, 32);
    float inv = 1.f / lsum;
    int nl = sub ? nl1 : nl0;
    unsigned short* op = attT + ((size_t)(b*1024 + nl))*512 + h*64;
    #pragma unroll
    for(int cf = 0; cf < 4; cf++){
      uint2 pr;
      pr.x = pk2n(acc[sub][cf][0]*inv, acc[sub][cf][1]*inv);
      pr.y = pk2n(acc[sub][cf][2]*inv, acc[sub][cf][3]*inv);
      *reinterpret_cast<uint2*>(op + 16*cf + 4*g) = pr;
    }
  }
}

// ---------------- proj GEMM (bf16 A and B via gl_lds, BK=64) + bias + residual ----------------
__global__ __launch_bounds__(256) void proj_mm(const unsigned short* __restrict__ A,
                                               const unsigned short* __restrict__ Bx,
                                               const float* __restrict__ bias,
                                               const float* __restrict__ resid,
                                               float* __restrict__ out){
  __shared__ __align__(16) unsigned short As[128*64], Bs[128*64];
  int tid = threadIdx.x;
  int n0 = blockIdx.x*128, o0 = blockIdx.y*128, b = blockIdx.z;
  int wid = tid >> 6, wr = wid >> 1, wc = wid & 1, ln = tid & 15, g = (tid >> 4) & 3;
  int l = tid & 63;
  int rsw = (ln & 7) << 3;
  int srow = 32*wid + (l >> 3);
  int scol = (((l & 7) ^ (l >> 3)) << 3);
  const unsigned short* Ag = A  + (size_t)(o0 + srow)*512 + scol;
  const unsigned short* Bg = Bx + ((size_t)(b*1024 + n0 + srow))*512 + scol;
  unsigned short* Asw = As + (32*wid)*64;
  unsigned short* Bsw = Bs + (32*wid)*64;
  f32x4 acc[4][4] = {};
  for(int k0 = 0; k0 < 512; k0 += 64){
    __syncthreads();
    #pragma unroll
    for(int c = 0; c < 4; c++){
      gl_lds16(Ag + (size_t)(8*c)*512 + k0, Asw + (8*c)*64);
      gl_lds16(Bg + (size_t)(8*c)*512 + k0, Bsw + (8*c)*64);
    }
    __syncthreads();
    #pragma unroll
    for(int kh = 0; kh < 2; kh++){
      int ro = (kh*32 + 8*g) ^ rsw;
      bf16x8 af[4], bfv[4];
      #pragma unroll
      for(int mf = 0; mf < 4; mf++)
        af[mf] = *reinterpret_cast<const bf16x8*>(&As[(wr*64 + 16*mf + ln)*64 + ro]);
      #pragma unroll
      for(int nf = 0; nf < 4; nf++)
        bfv[nf] = *reinterpret_cast<const bf16x8*>(&Bs[(wc*64 + 16*nf + ln)*64 + ro]);
      #pragma unroll
      for(int mf = 0; mf < 4; mf++)
        #pragma unroll
        for(int nf = 0; nf < 4; nf++)
          acc[mf][nf] = MFMA16(af[mf], bfv[nf], acc[mf][nf]);
    }
  }
  #pragma unroll
  for(int mf = 0; mf < 4; mf++)
    #pragma unroll
    for(int r = 0; r < 4; r++){
      int o = o0 + wr*64 + 16*mf + 4*g + r;
      float bo = bias[o];
      #pragma unroll
      for(int nf = 0; nf < 4; nf++){
        int n = n0 + wc*64 + 16*nf + ln;
        size_t off = ((size_t)(b*512 + o))*1024 + n;
        out[off] = acc[mf][nf][r] + bo + resid[off];
      }
    }
}

extern "C" void kernel_launch(void* const* d_in, const int* in_sizes, int n_in,
                              void* d_out, int out_size, void* d_ws, size_t ws_size,
                              hipStream_t stream){
  const float* x     = (const float*)d_in[0];
  const float* gnw   = (const float*)d_in[1];
  const float* gnb   = (const float*)d_in[2];
  const float* qkvw  = (const float*)d_in[3];
  const float* qkvb  = (const float*)d_in[4];
  const float* projw = (const float*)d_in[5];
  const float* projb = (const float*)d_in[6];
  float* out = (float*)d_out;

  char* w = (char*)d_ws;
  unsigned short* wqb = (unsigned short*)w;  w += (size_t)1536*512*2;
  unsigned short* wpb = (unsigned short*)w;  w += (size_t)512*512*2;
  unsigned short* xnT = (unsigned short*)w;  w += (size_t)16*1024*512*2;
  unsigned short* Tqk = (unsigned short*)w;  w += (size_t)16*1024*1024*2;
  unsigned short* Vb  = (unsigned short*)w;  w += (size_t)16*512*1024*2;
  unsigned short* attT = (unsigned short*)w; w += (size_t)16*1024*512*2;

  hipLaunchKernelGGL(wcvt_k, dim3(768), dim3(256), 0, stream, qkvw, (unsigned int*)wqb);
  hipLaunchKernelGGL(wcvt_k, dim3(256), dim3(256), 0, stream, projw, (unsigned int*)wpb);
  hipLaunchKernelGGL(gn_fused_k, dim3(128), dim3(512), 0, stream, x, gnw, gnb, xnT);
  hipLaunchKernelGGL(qkv_mm, dim3(8, 12, 16), dim3(256), 0, stream, wqb, xnT, qkvb, Tqk, Vb);
  hipLaunchKernelGGL(attn_bf_k, dim3(1024), dim3(256), 0, stream, Tqk, Vb, attT);
  hipLaunchKernelGGL(proj_mm, dim3(8, 4, 16), dim3(256), 0, stream, wpb, attT, projb, x, out);
}

// Round 13
// 159.714 us; speedup vs baseline: 1.0519x; 1.0519x over previous
//
#include <hip/hip_runtime.h>
#include <hip/hip_bf16.h>
#include <math.h>

typedef short bf16x8 __attribute__((ext_vector_type(8)));
typedef float f32x4  __attribute__((ext_vector_type(4)));
#define MFMA16(a,b,c) __builtin_amdgcn_mfma_f32_16x16x32_bf16(a,b,c,0,0,0)

#define EPSF 1e-5f
#define QSC 0.18033688f   // 0.125 * log2(e), folded into Q

#if __has_builtin(__builtin_amdgcn_exp2f)
#define EXP2(x) __builtin_amdgcn_exp2f(x)
#else
#define EXP2(x) exp2f(x)
#endif

__device__ __forceinline__ unsigned int pk2n(float a, float b){
  __hip_bfloat162 h = __float22bfloat162_rn(make_float2(a, b));
  return *reinterpret_cast<unsigned int*>(&h);
}
__device__ __forceinline__ unsigned short bfn(float f){
  __hip_bfloat16 h = __float2bfloat16(f);
  return *reinterpret_cast<unsigned short*>(&h);
}
__device__ __forceinline__ float4 ld4(const float* p){ return *reinterpret_cast<const float4*>(p); }
__device__ __forceinline__ void st4(float* p, float4 v){ *reinterpret_cast<float4*>(p) = v; }

// async global->LDS, 16B per lane; LDS dest = wave-uniform base + lane*16
__device__ __forceinline__ void gl_lds16(const unsigned short* g, unsigned short* l){
  __builtin_amdgcn_global_load_lds(
      (const __attribute__((address_space(1))) unsigned int*)g,
      (__attribute__((address_space(3))) unsigned int*)l, 16, 0, 0);
}

// ---------------- weight f32 -> bf16 ----------------
__global__ __launch_bounds__(256) void wcvt_k(const float* __restrict__ src,
                                              unsigned int* __restrict__ dst){
  int i = blockIdx.x * 256 + threadIdx.x;            // one float4 -> uint2
  float4 v = reinterpret_cast<const float4*>(src)[i];
  uint2 r; r.x = pk2n(v.x, v.y); r.y = pk2n(v.z, v.w);
  reinterpret_cast<uint2*>(dst)[i] = r;
}

// ---------------- fused GroupNorm stats + apply + transpose ----------------
__global__ __launch_bounds__(512) void gn_fused_k(const float* __restrict__ x,
                                                  const float* __restrict__ gnw,
                                                  const float* __restrict__ gnb,
                                                  unsigned short* __restrict__ xnT){
  __shared__ float Xl[2][64*65];
  __shared__ float red[16];
  int blk = blockIdx.x;                       // b*8+g
  int b = blk >> 3, g = blk & 7;
  int tid = threadIdx.x;
  const float4* p4 = reinterpret_cast<const float4*>(x + (size_t)blk * 65536);
  float s1 = 0.f, s2 = 0.f;
  for(int i = tid; i < 16384; i += 512){
    float4 v = p4[i];
    s1 += (v.x + v.y) + (v.z + v.w);
    s2 += v.x*v.x + v.y*v.y + v.z*v.z + v.w*v.w;
  }
  #pragma unroll
  for(int off = 32; off; off >>= 1){ s1 += __shfl_xor(s1, off); s2 += __shfl_xor(s2, off); }
  if((tid & 63) == 0){ red[tid >> 6] = s1; red[8 + (tid >> 6)] = s2; }
  __syncthreads();
  float a = 0.f, b2 = 0.f;
  #pragma unroll
  for(int w = 0; w < 8; w++){ a += red[w]; b2 += red[8 + w]; }
  float mean = a * (1.f / 65536.f);
  float rstd = rsqrtf(b2 * (1.f / 65536.f) - mean * mean + EPSF);
  int half = tid >> 8, t256 = tid & 255;
  int nq = t256 & 15, rr = t256 >> 4;
  int c0 = g * 64;
  for(int it = 0; it < 8; it++){
    int n0 = (it*2 + half) * 64;
    __syncthreads();
    #pragma unroll
    for(int p = 0; p < 4; p++){
      int cl = p * 16 + rr, c = c0 + cl;
      float s = rstd * gnw[c], t = gnb[c] - mean * s;
      float4 v = ld4(x + ((size_t)(b*512 + c))*1024 + n0 + 4*nq);
      Xl[half][(4*nq+0)*65 + cl] = v.x*s + t;
      Xl[half][(4*nq+1)*65 + cl] = v.y*s + t;
      Xl[half][(4*nq+2)*65 + cl] = v.z*s + t;
      Xl[half][(4*nq+3)*65 + cl] = v.w*s + t;
    }
    __syncthreads();
    int n = t256 >> 2, cq = t256 & 3;
    float f[16];
    #pragma unroll
    for(int k = 0; k < 16; k++) f[k] = Xl[half][n*65 + 16*cq + k];
    uint4 w0, w1;
    w0.x = pk2n(f[0],f[1]);  w0.y = pk2n(f[2],f[3]);  w0.z = pk2n(f[4],f[5]);  w0.w = pk2n(f[6],f[7]);
    w1.x = pk2n(f[8],f[9]);  w1.y = pk2n(f[10],f[11]);w1.z = pk2n(f[12],f[13]);w1.w = pk2n(f[14],f[15]);
    unsigned short* dp = xnT + ((size_t)(b*1024 + n0 + n))*512 + c0 + 16*cq;
    *reinterpret_cast<uint4*>(dp)     = w0;
    *reinterpret_cast<uint4*>(dp + 8) = w1;
  }
}

// ---- GEMM core: BK=64, gl_lds staging, XOR-swizzled linear LDS (r10 measured-best) ----

// ---------------- QKV GEMM: Q,K transposed (Q pre-scaled) + V natural ----------------
__global__ __launch_bounds__(256) void qkv_mm(const unsigned short* __restrict__ A,
                                              const unsigned short* __restrict__ Bx,
                                              const float* __restrict__ bias,
                                              unsigned short* __restrict__ T,
                                              unsigned short* __restrict__ V){
  __shared__ __align__(16) unsigned short As[128*64], Bs[128*64];
  int tid = threadIdx.x;
  int n0 = blockIdx.x*128, o0 = blockIdx.y*128, b = blockIdx.z;
  int wid = tid >> 6, wr = wid >> 1, wc = wid & 1, ln = tid & 15, g = (tid >> 4) & 3;
  int l = tid & 63;
  int rsw = (ln & 7) << 3;
  int srow = 32*wid + (l >> 3);
  int scol = (((l & 7) ^ (l >> 3)) << 3);
  const unsigned short* Ag = A  + (size_t)(o0 + srow)*512 + scol;
  const unsigned short* Bg = Bx + ((size_t)(b*1024 + n0 + srow))*512 + scol;
  unsigned short* Asw = As + (32*wid)*64;
  unsigned short* Bsw = Bs + (32*wid)*64;
  f32x4 acc[4][4] = {};
  for(int k0 = 0; k0 < 512; k0 += 64){
    __syncthreads();
    #pragma unroll
    for(int c = 0; c < 4; c++){
      gl_lds16(Ag + (size_t)(8*c)*512 + k0, Asw + (8*c)*64);
      gl_lds16(Bg + (size_t)(8*c)*512 + k0, Bsw + (8*c)*64);
    }
    __syncthreads();
    #pragma unroll
    for(int kh = 0; kh < 2; kh++){
      int ro = (kh*32 + 8*g) ^ rsw;
      bf16x8 af[4], bfv[4];
      #pragma unroll
      for(int mf = 0; mf < 4; mf++)
        af[mf] = *reinterpret_cast<const bf16x8*>(&As[(wr*64 + 16*mf + ln)*64 + ro]);
      #pragma unroll
      for(int nf = 0; nf < 4; nf++)
        bfv[nf] = *reinterpret_cast<const bf16x8*>(&Bs[(wc*64 + 16*nf + ln)*64 + ro]);
      #pragma unroll
      for(int mf = 0; mf < 4; mf++)
        #pragma unroll
        for(int nf = 0; nf < 4; nf++)
          acc[mf][nf] = MFMA16(af[mf], bfv[nf], acc[mf][nf]);
    }
  }
  int obase = o0 + wr*64, nbase = n0 + wc*64;
  __syncthreads();                                    // As/Bs reuse as scratch
  unsigned short* scr = (wid < 2 ? As : Bs) + (wid & 1) * 2560;   // 64 rows x 40 pitch
  float sc = (obase < 512) ? QSC : 1.0f;
  if(obase < 1024){
    #pragma unroll
    for(int h2 = 0; h2 < 2; h2++){
      asm volatile("s_waitcnt lgkmcnt(0)" ::: "memory");
      __builtin_amdgcn_sched_barrier(0);
      #pragma unroll
      for(int mf2 = 0; mf2 < 2; mf2++){
        int mf = 2*h2 + mf2;
        int og = obase + 16*mf + 4*g;
        float b0 = bias[og], b1 = bias[og+1], b2 = bias[og+2], b3 = bias[og+3];
        #pragma unroll
        for(int nf = 0; nf < 4; nf++){
          uint2 pr;
          pr.x = pk2n((acc[mf][nf][0]+b0)*sc, (acc[mf][nf][1]+b1)*sc);
          pr.y = pk2n((acc[mf][nf][2]+b2)*sc, (acc[mf][nf][3]+b3)*sc);
          *reinterpret_cast<uint2*>(&scr[(16*nf + ln)*40 + 16*mf2 + 4*g]) = pr;
        }
      }
      asm volatile("s_waitcnt lgkmcnt(0)" ::: "memory");
      __builtin_amdgcn_sched_barrier(0);
      const unsigned short* rp = &scr[l*40];
      uint4 r0 = *reinterpret_cast<const uint4*>(rp);
      uint4 r1 = *reinterpret_cast<const uint4*>(rp+8);
      uint4 r2 = *reinterpret_cast<const uint4*>(rp+16);
      uint4 r3 = *reinterpret_cast<const uint4*>(rp+24);
      unsigned short* dp = T + ((size_t)(b*1024 + nbase + l))*1024 + obase + 32*h2;
      *reinterpret_cast<uint4*>(dp)    = r0;
      *reinterpret_cast<uint4*>(dp+8)  = r1;
      *reinterpret_cast<uint4*>(dp+16) = r2;
      *reinterpret_cast<uint4*>(dp+24) = r3;
    }
  } else {
    #pragma unroll
    for(int h2 = 0; h2 < 2; h2++){
      asm volatile("s_waitcnt lgkmcnt(0)" ::: "memory");
      __builtin_amdgcn_sched_barrier(0);
      #pragma unroll
      for(int nf2 = 0; nf2 < 2; nf2++){
        int nf = 2*h2 + nf2;
        #pragma unroll
        for(int mf = 0; mf < 4; mf++){
          int og = obase + 16*mf + 4*g;
          #pragma unroll
          for(int r = 0; r < 4; r++)
            scr[(16*mf + 4*g + r)*40 + 16*nf2 + ln] = bfn(acc[mf][nf][r] + bias[og+r]);
        }
      }
      asm volatile("s_waitcnt lgkmcnt(0)" ::: "memory");
      __builtin_amdgcn_sched_barrier(0);
      const unsigned short* rp = &scr[l*40];
      uint4 r0 = *reinterpret_cast<const uint4*>(rp);
      uint4 r1 = *reinterpret_cast<const uint4*>(rp+8);
      uint4 r2 = *reinterpret_cast<const uint4*>(rp+16);
      uint4 r3 = *reinterpret_cast<const uint4*>(rp+24);
      unsigned short* dp = V + ((size_t)(b*512 + obase - 1024 + l))*1024 + nbase + 32*h2;
      *reinterpret_cast<uint4*>(dp)    = r0;
      *reinterpret_cast<uint4*>(dp+8)  = r1;
      *reinterpret_cast<uint4*>(dp+16) = r2;
      *reinterpret_cast<uint4*>(dp+24) = r3;
    }
  }
}

// ---------------- Flash attention (r11 64-row form): gload_lds staging, XOR-swizzled
// LDS, dbuf K+V, 1 barrier/tile, no-max exp2 softmax, l via ones-MFMA, setprio ----
__global__ __launch_bounds__(256) void attn_bf_k(const unsigned short* __restrict__ T,
                                                 const unsigned short* __restrict__ V,
                                                 unsigned short* __restrict__ attT){
  __shared__ __align__(16) unsigned short KT[2][64*64];
  __shared__ __align__(16) unsigned short Vt[2][64*64];
  __shared__ __align__(16) unsigned int   Pl[4*16*32];   // pitch 32 + XOR swizzle
  int tid = threadIdx.x;
  // XCD swizzle: all 16 n0-blocks of a head share id%8 (same XCD) -> K/V L2-resident
  int id = blockIdx.x;
  int bh = (id >> 7) * 8 + (id & 7);
  int n0 = ((id >> 3) & 15) * 64;
  int b = bh >> 3, h = bh & 7;
  int wq = tid >> 6, ln = tid & 15, g = (tid >> 4) & 3;
  int l = tid & 63;
  int nl = n0 + wq*16 + ln;                 // this lane's q-row
  const unsigned short* Tb = T + ((size_t)b << 20);
  bf16x8 qf0 = *reinterpret_cast<const bf16x8*>(Tb + (size_t)nl*1024 + h*64 + 8*g);
  bf16x8 qf1 = *reinterpret_cast<const bf16x8*>(Tb + (size_t)nl*1024 + h*64 + 32 + 8*g);
  f32x4 acc[4] = {};
  f32x4 accl = {};                          // row-sum accumulator via ones-MFMA
  const short one_bf = (short)0x3F80;       // bf16 1.0
  bf16x8 ones8 = {one_bf,one_bf,one_bf,one_bf,one_bf,one_bf,one_bf,one_bf};
  const unsigned short* kg = Tb + 512 + h*64;
  const unsigned short* vg = V + ((size_t)(b*512 + h*64))*1024;
  int pbase = wq*512 + ln*32;
  int psw = (ln & 7) << 2;                  // Pl word swizzle
  int swz  = (((l & 7) << 3) ^ ((l >> 3) << 3));
  const unsigned short* ksrc = kg + (size_t)(wq*16 + (l>>3))*1024 + swz;
  const unsigned short* vsrc = vg + (size_t)(wq*16 + (l>>3))*1024 + swz;
  int rsw = (ln & 7) << 3;
  int ro0 = (8*g) ^ rsw, ro1 = (32 + 8*g) ^ rsw;
  // prologue: stage tile 0 into buffer 0
  {
    unsigned short* kb = &KT[0][wq*16*64];
    unsigned short* vb = &Vt[0][wq*16*64];
    gl_lds16(ksrc,            kb);
    gl_lds16(ksrc + 8*1024,   kb + 8*64);
    gl_lds16(vsrc,            vb);
    gl_lds16(vsrc + 8*1024,   vb + 8*64);
  }
  __syncthreads();
  for(int t = 0; t < 16; t++){
    int buf = t & 1;
    if(t < 15){          // stage tile t+1 into the other buffer (hidden under compute)
      int m1 = (t + 1) * 64;
      unsigned short* kb = &KT[buf^1][wq*16*64];
      unsigned short* vb = &Vt[buf^1][wq*16*64];
      gl_lds16(ksrc + (size_t)m1*1024,          kb);
      gl_lds16(ksrc + (size_t)(m1+8)*1024,      kb + 8*64);
      gl_lds16(vsrc + m1,                       vb);
      gl_lds16(vsrc + 8*1024 + m1,              vb + 8*64);
    }
    // QK^T from swizzled KT[buf]
    f32x4 sf[4];
    __builtin_amdgcn_s_setprio(1);
    #pragma unroll
    for(int mf = 0; mf < 4; mf++){
      bf16x8 a0 = *reinterpret_cast<const bf16x8*>(&KT[buf][(16*mf + ln)*64 + ro0]);
      bf16x8 a1 = *reinterpret_cast<const bf16x8*>(&KT[buf][(16*mf + ln)*64 + ro1]);
      f32x4 z = {0.f, 0.f, 0.f, 0.f};
      z = MFMA16(a0, qf0, z);
      sf[mf] = MFMA16(a1, qf1, z);
    }
    __builtin_amdgcn_s_setprio(0);
    // p = exp2(s); no max tracking (uniform scale cancels in the ratio)
    float p[16];
    #pragma unroll
    for(int mf = 0; mf < 4; mf++)
      #pragma unroll
      for(int r = 0; r < 4; r++)
        p[mf*4 + r] = EXP2(sf[mf][r]);
    // pack P (bf16 pairs) into per-wave LDS (XOR-swizzled), re-read as B-frags
    #pragma unroll
    for(int mt = 0; mt < 4; mt++){
      Pl[pbase + ((8*mt + 2*g + 0) ^ psw)] = pk2n(p[4*mt + 0], p[4*mt + 1]);
      Pl[pbase + ((8*mt + 2*g + 1) ^ psw)] = pk2n(p[4*mt + 2], p[4*mt + 3]);
    }
    asm volatile("s_waitcnt lgkmcnt(0)" ::: "memory");   // wave-local Pl ordering
    __builtin_amdgcn_sched_barrier(0);
    union { uint4 u; bf16x8 hv; } pb0, pb1;
    pb0.u = *reinterpret_cast<const uint4*>(&Pl[pbase + ((4*g) ^ psw)]);
    pb1.u = *reinterpret_cast<const uint4*>(&Pl[pbase + ((16 + 4*g) ^ psw)]);
    // PV from swizzled Vt[buf]; l row-sum via ones-MFMA (replaces 16 VALU adds)
    __builtin_amdgcn_s_setprio(1);
    accl = MFMA16(ones8, pb0.hv, accl);
    accl = MFMA16(ones8, pb1.hv, accl);
    #pragma unroll
    for(int cf = 0; cf < 4; cf++){
      bf16x8 v0 = *reinterpret_cast<const bf16x8*>(&Vt[buf][(16*cf + ln)*64 + ro0]);
      bf16x8 v1 = *reinterpret_cast<const bf16x8*>(&Vt[buf][(16*cf + ln)*64 + ro1]);
      acc[cf] = MFMA16(v0, pb0.hv, acc[cf]);
      acc[cf] = MFMA16(v1, pb1.hv, acc[cf]);
    }
    __builtin_amdgcn_s_setprio(0);
    // one barrier per tile: drains staging (issued a full tile of compute ago)
    // and fences buffer reuse for the next iteration
    __syncthreads();
  }
  float inv = 1.f / accl[0];                // every lane holds l[n=ln] in all 4 rows
  unsigned short* op = attT + ((size_t)(b*1024 + nl))*512 + h*64;
  #pragma unroll
  for(int cf = 0; cf < 4; cf++){
    uint2 pr;
    pr.x = pk2n(acc[cf][0]*inv, acc[cf][1]*inv);
    pr.y = pk2n(acc[cf][2]*inv, acc[cf][3]*inv);
    *reinterpret_cast<uint2*>(op + 16*cf + 4*g) = pr;
  }
}

// ---------------- proj GEMM (bf16 A and B via gl_lds, BK=64) + bias + residual ----------------
__global__ __launch_bounds__(256) void proj_mm(const unsigned short* __restrict__ A,
                                               const unsigned short* __restrict__ Bx,
                                               const float* __restrict__ bias,
                                               const float* __restrict__ resid,
                                               float* __restrict__ out){
  __shared__ __align__(16) unsigned short As[128*64], Bs[128*64];
  int tid = threadIdx.x;
  int n0 = blockIdx.x*128, o0 = blockIdx.y*128, b = blockIdx.z;
  int wid = tid >> 6, wr = wid >> 1, wc = wid & 1, ln = tid & 15, g = (tid >> 4) & 3;
  int l = tid & 63;
  int rsw = (ln & 7) << 3;
  int srow = 32*wid + (l >> 3);
  int scol = (((l & 7) ^ (l >> 3)) << 3);
  const unsigned short* Ag = A  + (size_t)(o0 + srow)*512 + scol;
  const unsigned short* Bg = Bx + ((size_t)(b*1024 + n0 + srow))*512 + scol;
  unsigned short* Asw = As + (32*wid)*64;
  unsigned short* Bsw = Bs + (32*wid)*64;
  f32x4 acc[4][4] = {};
  for(int k0 = 0; k0 < 512; k0 += 64){
    __syncthreads();
    #pragma unroll
    for(int c = 0; c < 4; c++){
      gl_lds16(Ag + (size_t)(8*c)*512 + k0, Asw + (8*c)*64);
      gl_lds16(Bg + (size_t)(8*c)*512 + k0, Bsw + (8*c)*64);
    }
    __syncthreads();
    #pragma unroll
    for(int kh = 0; kh < 2; kh++){
      int ro = (kh*32 + 8*g) ^ rsw;
      bf16x8 af[4], bfv[4];
      #pragma unroll
      for(int mf = 0; mf < 4; mf++)
        af[mf] = *reinterpret_cast<const bf16x8*>(&As[(wr*64 + 16*mf + ln)*64 + ro]);
      #pragma unroll
      for(int nf = 0; nf < 4; nf++)
        bfv[nf] = *reinterpret_cast<const bf16x8*>(&Bs[(wc*64 + 16*nf + ln)*64 + ro]);
      #pragma unroll
      for(int mf = 0; mf < 4; mf++)
        #pragma unroll
        for(int nf = 0; nf < 4; nf++)
          acc[mf][nf] = MFMA16(af[mf], bfv[nf], acc[mf][nf]);
    }
  }
  #pragma unroll
  for(int mf = 0; mf < 4; mf++)
    #pragma unroll
    for(int r = 0; r < 4; r++){
      int o = o0 + wr*64 + 16*mf + 4*g + r;
      float bo = bias[o];
      #pragma unroll
      for(int nf = 0; nf < 4; nf++){
        int n = n0 + wc*64 + 16*nf + ln;
        size_t off = ((size_t)(b*512 + o))*1024 + n;
        out[off] = acc[mf][nf][r] + bo + resid[off];
      }
    }
}

extern "C" void kernel_launch(void* const* d_in, const int* in_sizes, int n_in,
                              void* d_out, int out_size, void* d_ws, size_t ws_size,
                              hipStream_t stream){
  const float* x     = (const float*)d_in[0];
  const float* gnw   = (const float*)d_in[1];
  const float* gnb   = (const float*)d_in[2];
  const float* qkvw  = (const float*)d_in[3];
  const float* qkvb  = (const float*)d_in[4];
  const float* projw = (const float*)d_in[5];
  const float* projb = (const float*)d_in[6];
  float* out = (float*)d_out;

  char* w = (char*)d_ws;
  unsigned short* wqb = (unsigned short*)w;  w += (size_t)1536*512*2;
  unsigned short* wpb = (unsigned short*)w;  w += (size_t)512*512*2;
  unsigned short* xnT = (unsigned short*)w;  w += (size_t)16*1024*512*2;
  unsigned short* Tqk = (unsigned short*)w;  w += (size_t)16*1024*1024*2;
  unsigned short* Vb  = (unsigned short*)w;  w += (size_t)16*512*1024*2;
  unsigned short* attT = (unsigned short*)w; w += (size_t)16*1024*512*2;

  hipLaunchKernelGGL(wcvt_k, dim3(768), dim3(256), 0, stream, qkvw, (unsigned int*)wqb);
  hipLaunchKernelGGL(wcvt_k, dim3(256), dim3(256), 0, stream, projw, (unsigned int*)wpb);
  hipLaunchKernelGGL(gn_fused_k, dim3(128), dim3(512), 0, stream, x, gnw, gnb, xnT);
  hipLaunchKernelGGL(qkv_mm, dim3(8, 12, 16), dim3(256), 0, stream, wqb, xnT, qkvb, Tqk, Vb);
  hipLaunchKernelGGL(attn_bf_k, dim3(2048), dim3(256), 0, stream, Tqk, Vb, attT);
  hipLaunchKernelGGL(proj_mm, dim3(8, 4, 16), dim3(256), 0, stream, wpb, attT, projb, x, out);
}

// Round 14
// 151.897 us; speedup vs baseline: 1.1060x; 1.0515x over previous
//
#include <hip/hip_runtime.h>
#include <hip/hip_bf16.h>
#include <math.h>

typedef short bf16x8 __attribute__((ext_vector_type(8)));
typedef float f32x4  __attribute__((ext_vector_type(4)));
#define MFMA16(a,b,c) __builtin_amdgcn_mfma_f32_16x16x32_bf16(a,b,c,0,0,0)

#define EPSF 1e-5f
#define QSC 0.18033688f   // 0.125 * log2(e), folded into Q

#if __has_builtin(__builtin_amdgcn_exp2f)
#define EXP2(x) __builtin_amdgcn_exp2f(x)
#else
#define EXP2(x) exp2f(x)
#endif

__device__ __forceinline__ unsigned int pk2n(float a, float b){
  __hip_bfloat162 h = __float22bfloat162_rn(make_float2(a, b));
  return *reinterpret_cast<unsigned int*>(&h);
}
__device__ __forceinline__ unsigned short bfn(float f){
  __hip_bfloat16 h = __float2bfloat16(f);
  return *reinterpret_cast<unsigned short*>(&h);
}
__device__ __forceinline__ float4 ld4(const float* p){ return *reinterpret_cast<const float4*>(p); }

// async global->LDS, 16B per lane; LDS dest = wave-uniform base + lane*16
__device__ __forceinline__ void gl_lds16(const unsigned short* g, unsigned short* l){
  __builtin_amdgcn_global_load_lds(
      (const __attribute__((address_space(1))) unsigned int*)g,
      (__attribute__((address_space(3))) unsigned int*)l, 16, 0, 0);
}

// ---------------- preamble: fused GroupNorm (blocks 0..127) + weight cvt (blocks 128..383) ----------------
__global__ __launch_bounds__(512) void pre_k(const float* __restrict__ x,
                                             const float* __restrict__ gnw,
                                             const float* __restrict__ gnb,
                                             unsigned short* __restrict__ xnT,
                                             const float* __restrict__ qkvw,
                                             const float* __restrict__ projw,
                                             unsigned int* __restrict__ wqb,
                                             unsigned int* __restrict__ wpb){
  __shared__ float Xl[2][64*65];
  __shared__ float red[16];
  int blk = blockIdx.x;
  int tid = threadIdx.x;
  if(blk >= 128){
    // weight f32 -> bf16, 2 float4 per thread
    const float* src; unsigned int* dst; int base;
    if(blk < 320){ src = qkvw; dst = wqb; base = 128; }
    else         { src = projw; dst = wpb; base = 320; }
    int i = (blk - base)*1024 + tid*2;
    #pragma unroll
    for(int j = 0; j < 2; j++){
      float4 v = reinterpret_cast<const float4*>(src)[i + j];
      uint2 r; r.x = pk2n(v.x, v.y); r.y = pk2n(v.z, v.w);
      reinterpret_cast<uint2*>(dst)[i + j] = r;
    }
    return;
  }
  // GroupNorm: one block per (b, group); group slice (256 KB) L2-hot for pass 2
  int b = blk >> 3, g = blk & 7;
  const float4* p4 = reinterpret_cast<const float4*>(x + (size_t)blk * 65536);
  float s1 = 0.f, s2 = 0.f;
  for(int i = tid; i < 16384; i += 512){
    float4 v = p4[i];
    s1 += (v.x + v.y) + (v.z + v.w);
    s2 += v.x*v.x + v.y*v.y + v.z*v.z + v.w*v.w;
  }
  #pragma unroll
  for(int off = 32; off; off >>= 1){ s1 += __shfl_xor(s1, off); s2 += __shfl_xor(s2, off); }
  if((tid & 63) == 0){ red[tid >> 6] = s1; red[8 + (tid >> 6)] = s2; }
  __syncthreads();
  float a = 0.f, b2 = 0.f;
  #pragma unroll
  for(int w = 0; w < 8; w++){ a += red[w]; b2 += red[8 + w]; }
  float mean = a * (1.f / 65536.f);
  float rstd = rsqrtf(b2 * (1.f / 65536.f) - mean * mean + EPSF);
  int half = tid >> 8, t256 = tid & 255;
  int nq = t256 & 15, rr = t256 >> 4;
  int c0 = g * 64;
  for(int it = 0; it < 8; it++){
    int n0 = (it*2 + half) * 64;
    __syncthreads();
    #pragma unroll
    for(int p = 0; p < 4; p++){
      int cl = p * 16 + rr, c = c0 + cl;
      float s = rstd * gnw[c], t = gnb[c] - mean * s;
      float4 v = ld4(x + ((size_t)(b*512 + c))*1024 + n0 + 4*nq);
      Xl[half][(4*nq+0)*65 + cl] = v.x*s + t;
      Xl[half][(4*nq+1)*65 + cl] = v.y*s + t;
      Xl[half][(4*nq+2)*65 + cl] = v.z*s + t;
      Xl[half][(4*nq+3)*65 + cl] = v.w*s + t;
    }
    __syncthreads();
    int n = t256 >> 2, cq = t256 & 3;
    float f[16];
    #pragma unroll
    for(int k = 0; k < 16; k++) f[k] = Xl[half][n*65 + 16*cq + k];
    uint4 w0, w1;
    w0.x = pk2n(f[0],f[1]);  w0.y = pk2n(f[2],f[3]);  w0.z = pk2n(f[4],f[5]);  w0.w = pk2n(f[6],f[7]);
    w1.x = pk2n(f[8],f[9]);  w1.y = pk2n(f[10],f[11]);w1.z = pk2n(f[12],f[13]);w1.w = pk2n(f[14],f[15]);
    unsigned short* dp = xnT + ((size_t)(b*1024 + n0 + n))*512 + c0 + 16*cq;
    *reinterpret_cast<uint4*>(dp)     = w0;
    *reinterpret_cast<uint4*>(dp + 8) = w1;
  }
}

// ---- GEMM core: BK=64, gl_lds staging, XOR-swizzled linear LDS (r10 measured-best) ----

// ---------------- QKV GEMM: Q,K transposed (Q pre-scaled) + V natural ----------------
__global__ __launch_bounds__(256) void qkv_mm(const unsigned short* __restrict__ A,
                                              const unsigned short* __restrict__ Bx,
                                              const float* __restrict__ bias,
                                              unsigned short* __restrict__ T,
                                              unsigned short* __restrict__ V){
  __shared__ __align__(16) unsigned short As[128*64], Bs[128*64];
  int tid = threadIdx.x;
  int n0 = blockIdx.x*128, o0 = blockIdx.y*128, b = blockIdx.z;
  int wid = tid >> 6, wr = wid >> 1, wc = wid & 1, ln = tid & 15, g = (tid >> 4) & 3;
  int l = tid & 63;
  int rsw = (ln & 7) << 3;
  int srow = 32*wid + (l >> 3);
  int scol = (((l & 7) ^ (l >> 3)) << 3);
  const unsigned short* Ag = A  + (size_t)(o0 + srow)*512 + scol;
  const unsigned short* Bg = Bx + ((size_t)(b*1024 + n0 + srow))*512 + scol;
  unsigned short* Asw = As + (32*wid)*64;
  unsigned short* Bsw = Bs + (32*wid)*64;
  f32x4 acc[4][4] = {};
  for(int k0 = 0; k0 < 512; k0 += 64){
    __syncthreads();
    #pragma unroll
    for(int c = 0; c < 4; c++){
      gl_lds16(Ag + (size_t)(8*c)*512 + k0, Asw + (8*c)*64);
      gl_lds16(Bg + (size_t)(8*c)*512 + k0, Bsw + (8*c)*64);
    }
    __syncthreads();
    #pragma unroll
    for(int kh = 0; kh < 2; kh++){
      int ro = (kh*32 + 8*g) ^ rsw;
      bf16x8 af[4], bfv[4];
      #pragma unroll
      for(int mf = 0; mf < 4; mf++)
        af[mf] = *reinterpret_cast<const bf16x8*>(&As[(wr*64 + 16*mf + ln)*64 + ro]);
      #pragma unroll
      for(int nf = 0; nf < 4; nf++)
        bfv[nf] = *reinterpret_cast<const bf16x8*>(&Bs[(wc*64 + 16*nf + ln)*64 + ro]);
      #pragma unroll
      for(int mf = 0; mf < 4; mf++)
        #pragma unroll
        for(int nf = 0; nf < 4; nf++)
          acc[mf][nf] = MFMA16(af[mf], bfv[nf], acc[mf][nf]);
    }
  }
  int obase = o0 + wr*64, nbase = n0 + wc*64;
  __syncthreads();                                    // As/Bs reuse as scratch
  unsigned short* scr = (wid < 2 ? As : Bs) + (wid & 1) * 2560;   // 64 rows x 40 pitch
  float sc = (obase < 512) ? QSC : 1.0f;
  if(obase < 1024){
    #pragma unroll
    for(int h2 = 0; h2 < 2; h2++){
      asm volatile("s_waitcnt lgkmcnt(0)" ::: "memory");
      __builtin_amdgcn_sched_barrier(0);
      #pragma unroll
      for(int mf2 = 0; mf2 < 2; mf2++){
        int mf = 2*h2 + mf2;
        int og = obase + 16*mf + 4*g;
        float b0 = bias[og], b1 = bias[og+1], b2 = bias[og+2], b3 = bias[og+3];
        #pragma unroll
        for(int nf = 0; nf < 4; nf++){
          uint2 pr;
          pr.x = pk2n((acc[mf][nf][0]+b0)*sc, (acc[mf][nf][1]+b1)*sc);
          pr.y = pk2n((acc[mf][nf][2]+b2)*sc, (acc[mf][nf][3]+b3)*sc);
          *reinterpret_cast<uint2*>(&scr[(16*nf + ln)*40 + 16*mf2 + 4*g]) = pr;
        }
      }
      asm volatile("s_waitcnt lgkmcnt(0)" ::: "memory");
      __builtin_amdgcn_sched_barrier(0);
      const unsigned short* rp = &scr[l*40];
      uint4 r0 = *reinterpret_cast<const uint4*>(rp);
      uint4 r1 = *reinterpret_cast<const uint4*>(rp+8);
      uint4 r2 = *reinterpret_cast<const uint4*>(rp+16);
      uint4 r3 = *reinterpret_cast<const uint4*>(rp+24);
      unsigned short* dp = T + ((size_t)(b*1024 + nbase + l))*1024 + obase + 32*h2;
      *reinterpret_cast<uint4*>(dp)    = r0;
      *reinterpret_cast<uint4*>(dp+8)  = r1;
      *reinterpret_cast<uint4*>(dp+16) = r2;
      *reinterpret_cast<uint4*>(dp+24) = r3;
    }
  } else {
    #pragma unroll
    for(int h2 = 0; h2 < 2; h2++){
      asm volatile("s_waitcnt lgkmcnt(0)" ::: "memory");
      __builtin_amdgcn_sched_barrier(0);
      #pragma unroll
      for(int nf2 = 0; nf2 < 2; nf2++){
        int nf = 2*h2 + nf2;
        #pragma unroll
        for(int mf = 0; mf < 4; mf++){
          int og = obase + 16*mf + 4*g;
          #pragma unroll
          for(int r = 0; r < 4; r++)
            scr[(16*mf + 4*g + r)*40 + 16*nf2 + ln] = bfn(acc[mf][nf][r] + bias[og+r]);
        }
      }
      asm volatile("s_waitcnt lgkmcnt(0)" ::: "memory");
      __builtin_amdgcn_sched_barrier(0);
      const unsigned short* rp = &scr[l*40];
      uint4 r0 = *reinterpret_cast<const uint4*>(rp);
      uint4 r1 = *reinterpret_cast<const uint4*>(rp+8);
      uint4 r2 = *reinterpret_cast<const uint4*>(rp+16);
      uint4 r3 = *reinterpret_cast<const uint4*>(rp+24);
      unsigned short* dp = V + ((size_t)(b*512 + obase - 1024 + l))*1024 + nbase + 32*h2;
      *reinterpret_cast<uint4*>(dp)    = r0;
      *reinterpret_cast<uint4*>(dp+8)  = r1;
      *reinterpret_cast<uint4*>(dp+16) = r2;
      *reinterpret_cast<uint4*>(dp+24) = r3;
    }
  }
}

// ---------------- Flash attention (r11 measured-best, 66.3 us): gload_lds staging,
// XOR-swizzled LDS, dbuf K+V, 1 barrier/tile, no-max exp2 softmax, Pl repack ----
__global__ __launch_bounds__(256) void attn_bf_k(const unsigned short* __restrict__ T,
                                                 const unsigned short* __restrict__ V,
                                                 unsigned short* __restrict__ attT){
  __shared__ __align__(16) unsigned short KT[2][64*64];
  __shared__ __align__(16) unsigned short Vt[2][64*64];
  __shared__ __align__(16) unsigned int   Pl[4*16*32];   // pitch 32 + XOR swizzle
  int tid = threadIdx.x;
  // XCD swizzle: all 16 n0-blocks of a head share id%8 (same XCD) -> K/V L2-resident
  int id = blockIdx.x;
  int bh = (id >> 7) * 8 + (id & 7);
  int n0 = ((id >> 3) & 15) * 64;
  int b = bh >> 3, h = bh & 7;
  int wq = tid >> 6, ln = tid & 15, g = (tid >> 4) & 3;
  int l = tid & 63;
  int nl = n0 + wq*16 + ln;                 // this lane's q-row
  const unsigned short* Tb = T + ((size_t)b << 20);
  bf16x8 qf0 = *reinterpret_cast<const bf16x8*>(Tb + (size_t)nl*1024 + h*64 + 8*g);
  bf16x8 qf1 = *reinterpret_cast<const bf16x8*>(Tb + (size_t)nl*1024 + h*64 + 32 + 8*g);
  f32x4 acc[4] = {};
  float l_part = 0.f;
  const unsigned short* kg = Tb + 512 + h*64;
  const unsigned short* vg = V + ((size_t)(b*512 + h*64))*1024;
  int pbase = wq*512 + ln*32;
  int psw = (ln & 7) << 2;                  // Pl word swizzle
  int swz  = (((l & 7) << 3) ^ ((l >> 3) << 3));
  const unsigned short* ksrc = kg + (size_t)(wq*16 + (l>>3))*1024 + swz;
  const unsigned short* vsrc = vg + (size_t)(wq*16 + (l>>3))*1024 + swz;
  int rsw = (ln & 7) << 3;
  int ro0 = (8*g) ^ rsw, ro1 = (32 + 8*g) ^ rsw;
  // prologue: stage tile 0 into buffer 0
  {
    unsigned short* kb = &KT[0][wq*16*64];
    unsigned short* vb = &Vt[0][wq*16*64];
    gl_lds16(ksrc,            kb);
    gl_lds16(ksrc + 8*1024,   kb + 8*64);
    gl_lds16(vsrc,            vb);
    gl_lds16(vsrc + 8*1024,   vb + 8*64);
  }
  __syncthreads();
  for(int t = 0; t < 16; t++){
    int buf = t & 1;
    if(t < 15){          // stage tile t+1 into the other buffer (hidden under compute)
      int m1 = (t + 1) * 64;
      unsigned short* kb = &KT[buf^1][wq*16*64];
      unsigned short* vb = &Vt[buf^1][wq*16*64];
      gl_lds16(ksrc + (size_t)m1*1024,          kb);
      gl_lds16(ksrc + (size_t)(m1+8)*1024,      kb + 8*64);
      gl_lds16(vsrc + m1,                       vb);
      gl_lds16(vsrc + 8*1024 + m1,              vb + 8*64);
    }
    // QK^T from swizzled KT[buf]
    f32x4 sf[4];
    #pragma unroll
    for(int mf = 0; mf < 4; mf++){
      bf16x8 a0 = *reinterpret_cast<const bf16x8*>(&KT[buf][(16*mf + ln)*64 + ro0]);
      bf16x8 a1 = *reinterpret_cast<const bf16x8*>(&KT[buf][(16*mf + ln)*64 + ro1]);
      f32x4 z = {0.f, 0.f, 0.f, 0.f};
      z = MFMA16(a0, qf0, z);
      sf[mf] = MFMA16(a1, qf1, z);
    }
    // p = exp2(s); per-lane l partial (no max tracking: scale cancels in the ratio)
    float p[16];
    #pragma unroll
    for(int mf = 0; mf < 4; mf++)
      #pragma unroll
      for(int r = 0; r < 4; r++){
        float v = EXP2(sf[mf][r]);
        p[mf*4 + r] = v;
        l_part += v;
      }
    // pack P (bf16 pairs) into per-wave LDS (XOR-swizzled), re-read as B-frags
    #pragma unroll
    for(int mt = 0; mt < 4; mt++){
      Pl[pbase + ((8*mt + 2*g + 0) ^ psw)] = pk2n(p[4*mt + 0], p[4*mt + 1]);
      Pl[pbase + ((8*mt + 2*g + 1) ^ psw)] = pk2n(p[4*mt + 2], p[4*mt + 3]);
    }
    asm volatile("s_waitcnt lgkmcnt(0)" ::: "memory");   // wave-local Pl ordering
    __builtin_amdgcn_sched_barrier(0);
    union { uint4 u; bf16x8 hv; } pb0, pb1;
    pb0.u = *reinterpret_cast<const uint4*>(&Pl[pbase + ((4*g) ^ psw)]);
    pb1.u = *reinterpret_cast<const uint4*>(&Pl[pbase + ((16 + 4*g) ^ psw)]);
    // PV from swizzled Vt[buf]
    #pragma unroll
    for(int cf = 0; cf < 4; cf++){
      bf16x8 v0 = *reinterpret_cast<const bf16x8*>(&Vt[buf][(16*cf + ln)*64 + ro0]);
      bf16x8 v1 = *reinterpret_cast<const bf16x8*>(&Vt[buf][(16*cf + ln)*64 + ro1]);
      acc[cf] = MFMA16(v0, pb0.hv, acc[cf]);
      acc[cf] = MFMA16(v1, pb1.hv, acc[cf]);
    }
    // one barrier per tile: drains staging (issued a full tile of compute ago)
    // and fences buffer reuse for the next iteration
    __syncthreads();
  }
  float lsum = l_part;
  lsum += __shfl_xor(lsum, 16);
  lsum += __shfl_xor(lsum, 32);
  float inv = 1.f / lsum;
  unsigned short* op = attT + ((size_t)(b*1024 + nl))*512 + h*64;
  #pragma unroll
  for(int cf = 0; cf < 4; cf++){
    uint2 pr;
    pr.x = pk2n(acc[cf][0]*inv, acc[cf][1]*inv);
    pr.y = pk2n(acc[cf][2]*inv, acc[cf][3]*inv);
    *reinterpret_cast<uint2*>(op + 16*cf + 4*g) = pr;
  }
}

// ---------------- proj GEMM (bf16 A and B via gl_lds, BK=64) + bias + residual ----------------
__global__ __launch_bounds__(256) void proj_mm(const unsigned short* __restrict__ A,
                                               const unsigned short* __restrict__ Bx,
                                               const float* __restrict__ bias,
                                               const float* __restrict__ resid,
                                               float* __restrict__ out){
  __shared__ __align__(16) unsigned short As[128*64], Bs[128*64];
  int tid = threadIdx.x;
  int n0 = blockIdx.x*128, o0 = blockIdx.y*128, b = blockIdx.z;
  int wid = tid >> 6, wr = wid >> 1, wc = wid & 1, ln = tid & 15, g = (tid >> 4) & 3;
  int l = tid & 63;
  int rsw = (ln & 7) << 3;
  int srow = 32*wid + (l >> 3);
  int scol = (((l & 7) ^ (l >> 3)) << 3);
  const unsigned short* Ag = A  + (size_t)(o0 + srow)*512 + scol;
  const unsigned short* Bg = Bx + ((size_t)(b*1024 + n0 + srow))*512 + scol;
  unsigned short* Asw = As + (32*wid)*64;
  unsigned short* Bsw = Bs + (32*wid)*64;
  f32x4 acc[4][4] = {};
  for(int k0 = 0; k0 < 512; k0 += 64){
    __syncthreads();
    #pragma unroll
    for(int c = 0; c < 4; c++){
      gl_lds16(Ag + (size_t)(8*c)*512 + k0, Asw + (8*c)*64);
      gl_lds16(Bg + (size_t)(8*c)*512 + k0, Bsw + (8*c)*64);
    }
    __syncthreads();
    #pragma unroll
    for(int kh = 0; kh < 2; kh++){
      int ro = (kh*32 + 8*g) ^ rsw;
      bf16x8 af[4], bfv[4];
      #pragma unroll
      for(int mf = 0; mf < 4; mf++)
        af[mf] = *reinterpret_cast<const bf16x8*>(&As[(wr*64 + 16*mf + ln)*64 + ro]);
      #pragma unroll
      for(int nf = 0; nf < 4; nf++)
        bfv[nf] = *reinterpret_cast<const bf16x8*>(&Bs[(wc*64 + 16*nf + ln)*64 + ro]);
      #pragma unroll
      for(int mf = 0; mf < 4; mf++)
        #pragma unroll
        for(int nf = 0; nf < 4; nf++)
          acc[mf][nf] = MFMA16(af[mf], bfv[nf], acc[mf][nf]);
    }
  }
  #pragma unroll
  for(int mf = 0; mf < 4; mf++)
    #pragma unroll
    for(int r = 0; r < 4; r++){
      int o = o0 + wr*64 + 16*mf + 4*g + r;
      float bo = bias[o];
      #pragma unroll
      for(int nf = 0; nf < 4; nf++){
        int n = n0 + wc*64 + 16*nf + ln;
        size_t off = ((size_t)(b*512 + o))*1024 + n;
        out[off] = acc[mf][nf][r] + bo + resid[off];
      }
    }
}

extern "C" void kernel_launch(void* const* d_in, const int* in_sizes, int n_in,
                              void* d_out, int out_size, void* d_ws, size_t ws_size,
                              hipStream_t stream){
  const float* x     = (const float*)d_in[0];
  const float* gnw   = (const float*)d_in[1];
  const float* gnb   = (const float*)d_in[2];
  const float* qkvw  = (const float*)d_in[3];
  const float* qkvb  = (const float*)d_in[4];
  const float* projw = (const float*)d_in[5];
  const float* projb = (const float*)d_in[6];
  float* out = (float*)d_out;

  char* w = (char*)d_ws;
  unsigned short* wqb = (unsigned short*)w;  w += (size_t)1536*512*2;
  unsigned short* wpb = (unsigned short*)w;  w += (size_t)512*512*2;
  unsigned short* xnT = (unsigned short*)w;  w += (size_t)16*1024*512*2;
  unsigned short* Tqk = (unsigned short*)w;  w += (size_t)16*1024*1024*2;
  unsigned short* Vb  = (unsigned short*)w;  w += (size_t)16*512*1024*2;
  unsigned short* attT = (unsigned short*)w; w += (size_t)16*1024*512*2;

  hipLaunchKernelGGL(pre_k, dim3(384), dim3(512), 0, stream,
                     x, gnw, gnb, xnT, qkvw, projw,
                     (unsigned int*)wqb, (unsigned int*)wpb);
  hipLaunchKernelGGL(qkv_mm, dim3(8, 12, 16), dim3(256), 0, stream, wqb, xnT, qkvb, Tqk, Vb);
  hipLaunchKernelGGL(attn_bf_k, dim3(2048), dim3(256), 0, stream, Tqk, Vb, attT);
  hipLaunchKernelGGL(proj_mm, dim3(8, 4, 16), dim3(256), 0, stream, wpb, attT, projb, x, out);
}

// Round 15
// 147.729 us; speedup vs baseline: 1.1372x; 1.0282x over previous
//
#include <hip/hip_runtime.h>
#include <hip/hip_bf16.h>
#include <math.h>

typedef short bf16x8 __attribute__((ext_vector_type(8)));
typedef float f32x4  __attribute__((ext_vector_type(4)));
#define MFMA16(a,b,c) __builtin_amdgcn_mfma_f32_16x16x32_bf16(a,b,c,0,0,0)

#define EPSF 1e-5f
#define QSC 0.18033688f   // 0.125 * log2(e), folded into Q

#if __has_builtin(__builtin_amdgcn_exp2f)
#define EXP2(x) __builtin_amdgcn_exp2f(x)
#else
#define EXP2(x) exp2f(x)
#endif

__device__ __forceinline__ unsigned int pk2n(float a, float b){
  __hip_bfloat162 h = __float22bfloat162_rn(make_float2(a, b));
  return *reinterpret_cast<unsigned int*>(&h);
}
__device__ __forceinline__ unsigned short bfn(float f){
  __hip_bfloat16 h = __float2bfloat16(f);
  return *reinterpret_cast<unsigned short*>(&h);
}
__device__ __forceinline__ float4 ld4(const float* p){ return *reinterpret_cast<const float4*>(p); }

// async global->LDS, 16B per lane; LDS dest = wave-uniform base + lane*16
__device__ __forceinline__ void gl_lds16(const unsigned short* g, unsigned short* l){
  __builtin_amdgcn_global_load_lds(
      (const __attribute__((address_space(1))) unsigned int*)g,
      (__attribute__((address_space(3))) unsigned int*)l, 16, 0, 0);
}

// ---------------- preamble: fused GroupNorm (blocks 0..127) + weight cvt (blocks 128..383) ----------------
__global__ __launch_bounds__(512) void pre_k(const float* __restrict__ x,
                                             const float* __restrict__ gnw,
                                             const float* __restrict__ gnb,
                                             unsigned short* __restrict__ xnT,
                                             const float* __restrict__ qkvw,
                                             const float* __restrict__ projw,
                                             unsigned int* __restrict__ wqb,
                                             unsigned int* __restrict__ wpb){
  __shared__ float Xl[2][64*65];
  __shared__ float red[16];
  int blk = blockIdx.x;
  int tid = threadIdx.x;
  if(blk >= 128){
    const float* src; unsigned int* dst; int base;
    if(blk < 320){ src = qkvw; dst = wqb; base = 128; }
    else         { src = projw; dst = wpb; base = 320; }
    int i = (blk - base)*1024 + tid*2;
    #pragma unroll
    for(int j = 0; j < 2; j++){
      float4 v = reinterpret_cast<const float4*>(src)[i + j];
      uint2 r; r.x = pk2n(v.x, v.y); r.y = pk2n(v.z, v.w);
      reinterpret_cast<uint2*>(dst)[i + j] = r;
    }
    return;
  }
  int b = blk >> 3, g = blk & 7;
  const float4* p4 = reinterpret_cast<const float4*>(x + (size_t)blk * 65536);
  float s1 = 0.f, s2 = 0.f;
  for(int i = tid; i < 16384; i += 512){
    float4 v = p4[i];
    s1 += (v.x + v.y) + (v.z + v.w);
    s2 += v.x*v.x + v.y*v.y + v.z*v.z + v.w*v.w;
  }
  #pragma unroll
  for(int off = 32; off; off >>= 1){ s1 += __shfl_xor(s1, off); s2 += __shfl_xor(s2, off); }
  if((tid & 63) == 0){ red[tid >> 6] = s1; red[8 + (tid >> 6)] = s2; }
  __syncthreads();
  float a = 0.f, b2 = 0.f;
  #pragma unroll
  for(int w = 0; w < 8; w++){ a += red[w]; b2 += red[8 + w]; }
  float mean = a * (1.f / 65536.f);
  float rstd = rsqrtf(b2 * (1.f / 65536.f) - mean * mean + EPSF);
  int half = tid >> 8, t256 = tid & 255;
  int nq = t256 & 15, rr = t256 >> 4;
  int c0 = g * 64;
  for(int it = 0; it < 8; it++){
    int n0 = (it*2 + half) * 64;
    __syncthreads();
    #pragma unroll
    for(int p = 0; p < 4; p++){
      int cl = p * 16 + rr, c = c0 + cl;
      float s = rstd * gnw[c], t = gnb[c] - mean * s;
      float4 v = ld4(x + ((size_t)(b*512 + c))*1024 + n0 + 4*nq);
      Xl[half][(4*nq+0)*65 + cl] = v.x*s + t;
      Xl[half][(4*nq+1)*65 + cl] = v.y*s + t;
      Xl[half][(4*nq+2)*65 + cl] = v.z*s + t;
      Xl[half][(4*nq+3)*65 + cl] = v.w*s + t;
    }
    __syncthreads();
    int n = t256 >> 2, cq = t256 & 3;
    float f[16];
    #pragma unroll
    for(int k = 0; k < 16; k++) f[k] = Xl[half][n*65 + 16*cq + k];
    uint4 w0, w1;
    w0.x = pk2n(f[0],f[1]);  w0.y = pk2n(f[2],f[3]);  w0.z = pk2n(f[4],f[5]);  w0.w = pk2n(f[6],f[7]);
    w1.x = pk2n(f[8],f[9]);  w1.y = pk2n(f[10],f[11]);w1.z = pk2n(f[12],f[13]);w1.w = pk2n(f[14],f[15]);
    unsigned short* dp = xnT + ((size_t)(b*1024 + n0 + n))*512 + c0 + 16*cq;
    *reinterpret_cast<uint4*>(dp)     = w0;
    *reinterpret_cast<uint4*>(dp + 8) = w1;
  }
}

// ---- GEMM core: BK=64 DOUBLE-buffered, counted vmcnt(8) + raw s_barrier (T4),
// gl_lds staging, XOR-swizzled linear LDS. Stage t+1 stays in flight across
// both barriers; no vmcnt(0) drain in the main loop. ----

// ---------------- QKV GEMM: Q,K transposed (Q pre-scaled) + V natural ----------------
__global__ __launch_bounds__(256) void qkv_mm(const unsigned short* __restrict__ A,
                                              const unsigned short* __restrict__ Bx,
                                              const float* __restrict__ bias,
                                              unsigned short* __restrict__ T,
                                              unsigned short* __restrict__ V){
  __shared__ __align__(16) unsigned short As[2][128*64], Bs[2][128*64];
  int tid = threadIdx.x;
  int n0 = blockIdx.x*128, o0 = blockIdx.y*128, b = blockIdx.z;
  int wid = tid >> 6, wr = wid >> 1, wc = wid & 1, ln = tid & 15, g = (tid >> 4) & 3;
  int l = tid & 63;
  int rsw = (ln & 7) << 3;
  int srow = 32*wid + (l >> 3);
  int scol = (((l & 7) ^ (l >> 3)) << 3);
  const unsigned short* Ag = A  + (size_t)(o0 + srow)*512 + scol;
  const unsigned short* Bg = Bx + ((size_t)(b*1024 + n0 + srow))*512 + scol;
  f32x4 acc[4][4] = {};
  // prologue: stage k-tile 0 into buf 0
  #pragma unroll
  for(int c = 0; c < 4; c++){
    gl_lds16(Ag + (size_t)(8*c)*512, &As[0][(32*wid + 8*c)*64]);
    gl_lds16(Bg + (size_t)(8*c)*512, &Bs[0][(32*wid + 8*c)*64]);
  }
  for(int t = 0; t < 8; t++){
    int buf = t & 1;
    if(t < 7){
      int k1 = (t + 1) * 64;
      #pragma unroll
      for(int c = 0; c < 4; c++){
        gl_lds16(Ag + (size_t)(8*c)*512 + k1, &As[buf^1][(32*wid + 8*c)*64]);
        gl_lds16(Bg + (size_t)(8*c)*512 + k1, &Bs[buf^1][(32*wid + 8*c)*64]);
      }
      asm volatile("s_waitcnt vmcnt(8)" ::: "memory");   // tile t's 8 loads done
    } else {
      asm volatile("s_waitcnt vmcnt(0)" ::: "memory");
    }
    __builtin_amdgcn_sched_barrier(0);
    __builtin_amdgcn_s_barrier();                        // all waves' t loads landed
    __builtin_amdgcn_sched_barrier(0);
    #pragma unroll
    for(int kh = 0; kh < 2; kh++){
      int ro = (kh*32 + 8*g) ^ rsw;
      bf16x8 af[4], bfv[4];
      #pragma unroll
      for(int mf = 0; mf < 4; mf++)
        af[mf] = *reinterpret_cast<const bf16x8*>(&As[buf][(wr*64 + 16*mf + ln)*64 + ro]);
      #pragma unroll
      for(int nf = 0; nf < 4; nf++)
        bfv[nf] = *reinterpret_cast<const bf16x8*>(&Bs[buf][(wc*64 + 16*nf + ln)*64 + ro]);
      #pragma unroll
      for(int mf = 0; mf < 4; mf++)
        #pragma unroll
        for(int nf = 0; nf < 4; nf++)
          acc[mf][nf] = MFMA16(af[mf], bfv[nf], acc[mf][nf]);
    }
    __builtin_amdgcn_sched_barrier(0);
    __builtin_amdgcn_s_barrier();                        // readers done; buf may be overwritten
  }
  int obase = o0 + wr*64, nbase = n0 + wc*64;
  unsigned short* scr = &As[0][0] + wid * 2560;          // 64 rows x 40 pitch, per-wave scratch
  float sc = (obase < 512) ? QSC : 1.0f;
  if(obase < 1024){
    #pragma unroll
    for(int h2 = 0; h2 < 2; h2++){
      asm volatile("s_waitcnt lgkmcnt(0)" ::: "memory");
      __builtin_amdgcn_sched_barrier(0);
      #pragma unroll
      for(int mf2 = 0; mf2 < 2; mf2++){
        int mf = 2*h2 + mf2;
        int og = obase + 16*mf + 4*g;
        float b0 = bias[og], b1 = bias[og+1], b2 = bias[og+2], b3 = bias[og+3];
        #pragma unroll
        for(int nf = 0; nf < 4; nf++){
          uint2 pr;
          pr.x = pk2n((acc[mf][nf][0]+b0)*sc, (acc[mf][nf][1]+b1)*sc);
          pr.y = pk2n((acc[mf][nf][2]+b2)*sc, (acc[mf][nf][3]+b3)*sc);
          *reinterpret_cast<uint2*>(&scr[(16*nf + ln)*40 + 16*mf2 + 4*g]) = pr;
        }
      }
      asm volatile("s_waitcnt lgkmcnt(0)" ::: "memory");
      __builtin_amdgcn_sched_barrier(0);
      const unsigned short* rp = &scr[l*40];
      uint4 r0 = *reinterpret_cast<const uint4*>(rp);
      uint4 r1 = *reinterpret_cast<const uint4*>(rp+8);
      uint4 r2 = *reinterpret_cast<const uint4*>(rp+16);
      uint4 r3 = *reinterpret_cast<const uint4*>(rp+24);
      unsigned short* dp = T + ((size_t)(b*1024 + nbase + l))*1024 + obase + 32*h2;
      *reinterpret_cast<uint4*>(dp)    = r0;
      *reinterpret_cast<uint4*>(dp+8)  = r1;
      *reinterpret_cast<uint4*>(dp+16) = r2;
      *reinterpret_cast<uint4*>(dp+24) = r3;
    }
  } else {
    #pragma unroll
    for(int h2 = 0; h2 < 2; h2++){
      asm volatile("s_waitcnt lgkmcnt(0)" ::: "memory");
      __builtin_amdgcn_sched_barrier(0);
      #pragma unroll
      for(int nf2 = 0; nf2 < 2; nf2++){
        int nf = 2*h2 + nf2;
        #pragma unroll
        for(int mf = 0; mf < 4; mf++){
          int og = obase + 16*mf + 4*g;
          #pragma unroll
          for(int r = 0; r < 4; r++)
            scr[(16*mf + 4*g + r)*40 + 16*nf2 + ln] = bfn(acc[mf][nf][r] + bias[og+r]);
        }
      }
      asm volatile("s_waitcnt lgkmcnt(0)" ::: "memory");
      __builtin_amdgcn_sched_barrier(0);
      const unsigned short* rp = &scr[l*40];
      uint4 r0 = *reinterpret_cast<const uint4*>(rp);
      uint4 r1 = *reinterpret_cast<const uint4*>(rp+8);
      uint4 r2 = *reinterpret_cast<const uint4*>(rp+16);
      uint4 r3 = *reinterpret_cast<const uint4*>(rp+24);
      unsigned short* dp = V + ((size_t)(b*512 + obase - 1024 + l))*1024 + nbase + 32*h2;
      *reinterpret_cast<uint4*>(dp)    = r0;
      *reinterpret_cast<uint4*>(dp+8)  = r1;
      *reinterpret_cast<uint4*>(dp+16) = r2;
      *reinterpret_cast<uint4*>(dp+24) = r3;
    }
  }
}

// ---------------- Flash attention (r11 measured-best): gload_lds staging,
// XOR-swizzled LDS, dbuf K+V, 1 barrier/tile, no-max exp2 softmax, Pl repack ----
__global__ __launch_bounds__(256) void attn_bf_k(const unsigned short* __restrict__ T,
                                                 const unsigned short* __restrict__ V,
                                                 unsigned short* __restrict__ attT){
  __shared__ __align__(16) unsigned short KT[2][64*64];
  __shared__ __align__(16) unsigned short Vt[2][64*64];
  __shared__ __align__(16) unsigned int   Pl[4*16*32];   // pitch 32 + XOR swizzle
  int tid = threadIdx.x;
  int id = blockIdx.x;
  int bh = (id >> 7) * 8 + (id & 7);
  int n0 = ((id >> 3) & 15) * 64;
  int b = bh >> 3, h = bh & 7;
  int wq = tid >> 6, ln = tid & 15, g = (tid >> 4) & 3;
  int l = tid & 63;
  int nl = n0 + wq*16 + ln;
  const unsigned short* Tb = T + ((size_t)b << 20);
  bf16x8 qf0 = *reinterpret_cast<const bf16x8*>(Tb + (size_t)nl*1024 + h*64 + 8*g);
  bf16x8 qf1 = *reinterpret_cast<const bf16x8*>(Tb + (size_t)nl*1024 + h*64 + 32 + 8*g);
  f32x4 acc[4] = {};
  float l_part = 0.f;
  const unsigned short* kg = Tb + 512 + h*64;
  const unsigned short* vg = V + ((size_t)(b*512 + h*64))*1024;
  int pbase = wq*512 + ln*32;
  int psw = (ln & 7) << 2;
  int swz  = (((l & 7) << 3) ^ ((l >> 3) << 3));
  const unsigned short* ksrc = kg + (size_t)(wq*16 + (l>>3))*1024 + swz;
  const unsigned short* vsrc = vg + (size_t)(wq*16 + (l>>3))*1024 + swz;
  int rsw = (ln & 7) << 3;
  int ro0 = (8*g) ^ rsw, ro1 = (32 + 8*g) ^ rsw;
  {
    unsigned short* kb = &KT[0][wq*16*64];
    unsigned short* vb = &Vt[0][wq*16*64];
    gl_lds16(ksrc,            kb);
    gl_lds16(ksrc + 8*1024,   kb + 8*64);
    gl_lds16(vsrc,            vb);
    gl_lds16(vsrc + 8*1024,   vb + 8*64);
  }
  __syncthreads();
  for(int t = 0; t < 16; t++){
    int buf = t & 1;
    if(t < 15){
      int m1 = (t + 1) * 64;
      unsigned short* kb = &KT[buf^1][wq*16*64];
      unsigned short* vb = &Vt[buf^1][wq*16*64];
      gl_lds16(ksrc + (size_t)m1*1024,          kb);
      gl_lds16(ksrc + (size_t)(m1+8)*1024,      kb + 8*64);
      gl_lds16(vsrc + m1,                       vb);
      gl_lds16(vsrc + 8*1024 + m1,              vb + 8*64);
    }
    f32x4 sf[4];
    #pragma unroll
    for(int mf = 0; mf < 4; mf++){
      bf16x8 a0 = *reinterpret_cast<const bf16x8*>(&KT[buf][(16*mf + ln)*64 + ro0]);
      bf16x8 a1 = *reinterpret_cast<const bf16x8*>(&KT[buf][(16*mf + ln)*64 + ro1]);
      f32x4 z = {0.f, 0.f, 0.f, 0.f};
      z = MFMA16(a0, qf0, z);
      sf[mf] = MFMA16(a1, qf1, z);
    }
    float p[16];
    #pragma unroll
    for(int mf = 0; mf < 4; mf++)
      #pragma unroll
      for(int r = 0; r < 4; r++){
        float v = EXP2(sf[mf][r]);
        p[mf*4 + r] = v;
        l_part += v;
      }
    #pragma unroll
    for(int mt = 0; mt < 4; mt++){
      Pl[pbase + ((8*mt + 2*g + 0) ^ psw)] = pk2n(p[4*mt + 0], p[4*mt + 1]);
      Pl[pbase + ((8*mt + 2*g + 1) ^ psw)] = pk2n(p[4*mt + 2], p[4*mt + 3]);
    }
    asm volatile("s_waitcnt lgkmcnt(0)" ::: "memory");
    __builtin_amdgcn_sched_barrier(0);
    union { uint4 u; bf16x8 hv; } pb0, pb1;
    pb0.u = *reinterpret_cast<const uint4*>(&Pl[pbase + ((4*g) ^ psw)]);
    pb1.u = *reinterpret_cast<const uint4*>(&Pl[pbase + ((16 + 4*g) ^ psw)]);
    #pragma unroll
    for(int cf = 0; cf < 4; cf++){
      bf16x8 v0 = *reinterpret_cast<const bf16x8*>(&Vt[buf][(16*cf + ln)*64 + ro0]);
      bf16x8 v1 = *reinterpret_cast<const bf16x8*>(&Vt[buf][(16*cf + ln)*64 + ro1]);
      acc[cf] = MFMA16(v0, pb0.hv, acc[cf]);
      acc[cf] = MFMA16(v1, pb1.hv, acc[cf]);
    }
    __syncthreads();
  }
  float lsum = l_part;
  lsum += __shfl_xor(lsum, 16);
  lsum += __shfl_xor(lsum, 32);
  float inv = 1.f / lsum;
  unsigned short* op = attT + ((size_t)(b*1024 + nl))*512 + h*64;
  #pragma unroll
  for(int cf = 0; cf < 4; cf++){
    uint2 pr;
    pr.x = pk2n(acc[cf][0]*inv, acc[cf][1]*inv);
    pr.y = pk2n(acc[cf][2]*inv, acc[cf][3]*inv);
    *reinterpret_cast<uint2*>(op + 16*cf + 4*g) = pr;
  }
}

// ---------------- proj GEMM (bf16 A and B, BK=64 dbuf counted-vmcnt) + bias + residual ----------------
__global__ __launch_bounds__(256) void proj_mm(const unsigned short* __restrict__ A,
                                               const unsigned short* __restrict__ Bx,
                                               const float* __restrict__ bias,
                                               const float* __restrict__ resid,
                                               float* __restrict__ out){
  __shared__ __align__(16) unsigned short As[2][128*64], Bs[2][128*64];
  int tid = threadIdx.x;
  int n0 = blockIdx.x*128, o0 = blockIdx.y*128, b = blockIdx.z;
  int wid = tid >> 6, wr = wid >> 1, wc = wid & 1, ln = tid & 15, g = (tid >> 4) & 3;
  int l = tid & 63;
  int rsw = (ln & 7) << 3;
  int srow = 32*wid + (l >> 3);
  int scol = (((l & 7) ^ (l >> 3)) << 3);
  const unsigned short* Ag = A  + (size_t)(o0 + srow)*512 + scol;
  const unsigned short* Bg = Bx + ((size_t)(b*1024 + n0 + srow))*512 + scol;
  f32x4 acc[4][4] = {};
  #pragma unroll
  for(int c = 0; c < 4; c++){
    gl_lds16(Ag + (size_t)(8*c)*512, &As[0][(32*wid + 8*c)*64]);
    gl_lds16(Bg + (size_t)(8*c)*512, &Bs[0][(32*wid + 8*c)*64]);
  }
  for(int t = 0; t < 8; t++){
    int buf = t & 1;
    if(t < 7){
      int k1 = (t + 1) * 64;
      #pragma unroll
      for(int c = 0; c < 4; c++){
        gl_lds16(Ag + (size_t)(8*c)*512 + k1, &As[buf^1][(32*wid + 8*c)*64]);
        gl_lds16(Bg + (size_t)(8*c)*512 + k1, &Bs[buf^1][(32*wid + 8*c)*64]);
      }
      asm volatile("s_waitcnt vmcnt(8)" ::: "memory");
    } else {
      asm volatile("s_waitcnt vmcnt(0)" ::: "memory");
    }
    __builtin_amdgcn_sched_barrier(0);
    __builtin_amdgcn_s_barrier();
    __builtin_amdgcn_sched_barrier(0);
    #pragma unroll
    for(int kh = 0; kh < 2; kh++){
      int ro = (kh*32 + 8*g) ^ rsw;
      bf16x8 af[4], bfv[4];
      #pragma unroll
      for(int mf = 0; mf < 4; mf++)
        af[mf] = *reinterpret_cast<const bf16x8*>(&As[buf][(wr*64 + 16*mf + ln)*64 + ro]);
      #pragma unroll
      for(int nf = 0; nf < 4; nf++)
        bfv[nf] = *reinterpret_cast<const bf16x8*>(&Bs[buf][(wc*64 + 16*nf + ln)*64 + ro]);
      #pragma unroll
      for(int mf = 0; mf < 4; mf++)
        #pragma unroll
        for(int nf = 0; nf < 4; nf++)
          acc[mf][nf] = MFMA16(af[mf], bfv[nf], acc[mf][nf]);
    }
    __builtin_amdgcn_sched_barrier(0);
    __builtin_amdgcn_s_barrier();
  }
  #pragma unroll
  for(int mf = 0; mf < 4; mf++)
    #pragma unroll
    for(int r = 0; r < 4; r++){
      int o = o0 + wr*64 + 16*mf + 4*g + r;
      float bo = bias[o];
      #pragma unroll
      for(int nf = 0; nf < 4; nf++){
        int n = n0 + wc*64 + 16*nf + ln;
        size_t off = ((size_t)(b*512 + o))*1024 + n;
        out[off] = acc[mf][nf][r] + bo + resid[off];
      }
    }
}

extern "C" void kernel_launch(void* const* d_in, const int* in_sizes, int n_in,
                              void* d_out, int out_size, void* d_ws, size_t ws_size,
                              hipStream_t stream){
  const float* x     = (const float*)d_in[0];
  const float* gnw   = (const float*)d_in[1];
  const float* gnb   = (const float*)d_in[2];
  const float* qkvw  = (const float*)d_in[3];
  const float* qkvb  = (const float*)d_in[4];
  const float* projw = (const float*)d_in[5];
  const float* projb = (const float*)d_in[6];
  float* out = (float*)d_out;

  char* w = (char*)d_ws;
  unsigned short* wqb = (unsigned short*)w;  w += (size_t)1536*512*2;
  unsigned short* wpb = (unsigned short*)w;  w += (size_t)512*512*2;
  unsigned short* xnT = (unsigned short*)w;  w += (size_t)16*1024*512*2;
  unsigned short* Tqk = (unsigned short*)w;  w += (size_t)16*1024*1024*2;
  unsigned short* Vb  = (unsigned short*)w;  w += (size_t)16*512*1024*2;
  unsigned short* attT = (unsigned short*)w; w += (size_t)16*1024*512*2;

  hipLaunchKernelGGL(pre_k, dim3(384), dim3(512), 0, stream,
                     x, gnw, gnb, xnT, qkvw, projw,
                     (unsigned int*)wqb, (unsigned int*)wpb);
  hipLaunchKernelGGL(qkv_mm, dim3(8, 12, 16), dim3(256), 0, stream, wqb, xnT, qkvb, Tqk, Vb);
  hipLaunchKernelGGL(attn_bf_k, dim3(2048), dim3(256), 0, stream, Tqk, Vb, attT);
  hipLaunchKernelGGL(proj_mm, dim3(8, 4, 16), dim3(256), 0, stream, wpb, attT, projb, x, out);
}